// Round 3
// baseline (925.566 us; speedup 1.0000x reference)
//
#include <hip/hip_runtime.h>
#include <hip/hip_bf16.h>

#define NEMB  4096
#define DIM   128
#define NROWS 32768

#define BM 128
#define BN 128
#define KC 32
#define NSPLIT 4
#define TILES  8   // (NEMB/NSPLIT)/BN

// ---------------- K1: numpy-pairwise row sum of squares ----------------
// Replicates np.sum(a*a, axis=1) for n=128 float32 EXACTLY:
// 8 accumulators r[j] = sum_t a[8t+j] (sequential), then
// ((r0+r1)+(r2+r3)) + ((r4+r5)+(r6+r7)). 8 lanes per row.
__global__ void k_pairwise_sq(const float* __restrict__ src, float* __restrict__ dst) {
    const int wave = (blockIdx.x << 2) | (threadIdx.x >> 6);
    const int l    = threadIdx.x & 63;
    const int row  = wave * 8 + (l >> 3);
    const int j    = l & 7;
    const float* p = src + (size_t)row * DIM + j;
    float v = p[0];
    float r = __fmul_rn(v, v);
    #pragma unroll
    for (int t = 1; t < 16; ++t) {
        v = p[t * 8];
        r = __fadd_rn(r, __fmul_rn(v, v));
    }
    float o = __shfl_xor(r, 1, 64); r = __fadd_rn(r, o);   // (r0+r1), (r2+r3), ...
    o = __shfl_xor(r, 2, 64); r = __fadd_rn(r, o);         // (r0+r1)+(r2+r3), ...
    o = __shfl_xor(r, 4, 64); r = __fadd_rn(r, o);         // full tree
    if (j == 0) dst[row] = r;
}

// ---------------- K2: fp32 distances (numpy semantics) + per-split argmin ----------------
// d[r][c] = fl( fl(sxx[r] + sww[c]) - 2*dot[r][c] ), argmin with lowest-index ties.
__launch_bounds__(256)
__global__ void k_score(const float* __restrict__ x, const float* __restrict__ W,
                        const float* __restrict__ sxx, const float* __restrict__ sww,
                        float* __restrict__ pb_val, int* __restrict__ pb_idx) {
    // xs: [KC][132] k-major (pitch 132: 16B-aligned frags, reads broadcast+conflict-free)
    // ws: [KC][192] k-major, 16 frags of 8 codes at pitch 12 (16B-aligned, 2-way reads = free)
    __shared__ float smem[KC * 132 + KC * 192];
    float (*xs)[132] = (float (*)[132])smem;
    float (*ws)[192] = (float (*)[192])(smem + KC * 132);

    const int tid = threadIdx.x;
    const int tr  = tid >> 4;        // row group 0..15  (8 rows each)
    const int tc  = tid & 15;        // code group 0..15 (8 codes each)
    const int r0  = blockIdx.x * BM; // 256 row-blocks
    const int split = blockIdx.y;    // 4 code-splits of 1024 codes

    float sxxv[8];
    #pragma unroll
    for (int i = 0; i < 8; ++i) sxxv[i] = sxx[r0 + tr * 8 + i];

    float bestv[8];
    int   besti[8];
    #pragma unroll
    for (int i = 0; i < 8; ++i) { bestv[i] = 3.0e38f; besti[i] = 0; }

    for (int t = 0; t < TILES; ++t) {
        const int cb = split * (NEMB / NSPLIT) + t * BN;
        float acc[8][8];
        #pragma unroll
        for (int i = 0; i < 8; ++i)
            #pragma unroll
            for (int j = 0; j < 8; ++j) acc[i][j] = 0.0f;

        for (int k0 = 0; k0 < DIM; k0 += KC) {
            __syncthreads();
            // stage x chunk: 128 rows x 32 k
            #pragma unroll
            for (int j = 0; j < 4; ++j) {
                const int i4 = tid + 256 * j;      // 0..1023 float4s
                const int r  = i4 >> 3;
                const int k4 = i4 & 7;
                const float4 v = *(const float4*)(x + (size_t)(r0 + r) * DIM + k0 + k4 * 4);
                xs[k4 * 4 + 0][r] = v.x;
                xs[k4 * 4 + 1][r] = v.y;
                xs[k4 * 4 + 2][r] = v.z;
                xs[k4 * 4 + 3][r] = v.w;
            }
            // stage W tile: 128 codes x 32 k
            #pragma unroll
            for (int j = 0; j < 4; ++j) {
                const int i4 = tid + 256 * j;
                const int c  = i4 >> 3;
                const int k4 = i4 & 7;
                const float4 v = *(const float4*)(W + (size_t)(cb + c) * DIM + k0 + k4 * 4);
                float* dst = &ws[k4 * 4][(c >> 3) * 12 + (c & 7)];
                dst[0 * 192] = v.x; dst[1 * 192] = v.y; dst[2 * 192] = v.z; dst[3 * 192] = v.w;
            }
            __syncthreads();

            const float* xp = &xs[0][tr * 8];
            const float* wp = &ws[0][tc * 12];
            #pragma unroll
            for (int k = 0; k < KC; ++k) {
                const float4 a0 = *(const float4*)(xp);
                const float4 a1 = *(const float4*)(xp + 4);
                const float4 b0 = *(const float4*)(wp);
                const float4 b1 = *(const float4*)(wp + 4);
                xp += 132; wp += 192;
                const float xf[8] = {a0.x, a0.y, a0.z, a0.w, a1.x, a1.y, a1.z, a1.w};
                const float wf[8] = {b0.x, b0.y, b0.z, b0.w, b1.x, b1.y, b1.z, b1.w};
                #pragma unroll
                for (int i = 0; i < 8; ++i)
                    #pragma unroll
                    for (int jj = 0; jj < 8; ++jj)
                        acc[i][jj] = fmaf(xf[i], wf[jj], acc[i][jj]);
            }
        }
        // epilogue: d = fl( fl(sxx+sww) - 2*acc ), min with lowest-index ties.
        // per-thread scan is ascending in code (tiles asc, jj asc) -> strict < keeps lowest.
        #pragma unroll
        for (int jj = 0; jj < 8; ++jj) {
            const int code = cb + tc * 8 + jj;
            const float swwv = sww[code];
            #pragma unroll
            for (int i = 0; i < 8; ++i) {
                const float A = __fadd_rn(sxxv[i], swwv);
                const float d = __fsub_rn(A, __fmul_rn(2.0f, acc[i][jj]));
                if (d < bestv[i]) { bestv[i] = d; besti[i] = code; }
            }
        }
    }

    // cross-thread (16 tc groups) reduce per row, reusing smem
    __syncthreads();
    float* rv = smem;                      // [128][17]
    int*   ri = (int*)(smem + 128 * 17);   // [128][17]
    #pragma unroll
    for (int i = 0; i < 8; ++i) {
        rv[(tr * 8 + i) * 17 + tc] = bestv[i];
        ri[(tr * 8 + i) * 17 + tc] = besti[i];
    }
    __syncthreads();
    if (tid < 128) {
        float bv = rv[tid * 17 + 0];
        int   bi = ri[tid * 17 + 0];
        #pragma unroll
        for (int j = 1; j < 16; ++j) {
            const float v = rv[tid * 17 + j];
            const int   c = ri[tid * 17 + j];
            if (v < bv || (v == bv && c < bi)) { bv = v; bi = c; }
        }
        pb_val[split * NROWS + r0 + tid] = bv;
        pb_idx[split * NROWS + r0 + tid] = bi;
    }
}

// ---------------- K2b: merge 4 splits (min, lowest-index ties), write idx (f32) ----------------
__global__ void k_merge(const float* __restrict__ pb_val, const int* __restrict__ pb_idx,
                        int* __restrict__ best_idx, float* __restrict__ out_idx) {
    const int r = blockIdx.x * 256 + threadIdx.x;   // 32768
    float bv = pb_val[r];
    int   bi = pb_idx[r];
    #pragma unroll
    for (int s = 1; s < NSPLIT; ++s) {
        const float v = pb_val[s * NROWS + r];
        const int   c = pb_idx[s * NROWS + r];
        if (v < bv || (v == bv && c < bi)) { bv = v; bi = c; }
    }
    best_idx[r] = bi;
    out_idx[r] = (float)bi;
}

// ---------------- K3: gather quantized (x2 outputs, f32) + loss partials ----------------
__global__ void k_quant(const float* __restrict__ x, const float* __restrict__ W,
                        const int* __restrict__ best_idx,
                        float* __restrict__ out0, float* __restrict__ out1,
                        float* __restrict__ loss_acc) {
    const int row = blockIdx.x * 4 + (threadIdx.x >> 6);  // one wave per row
    const int l   = threadIdx.x & 63;
    const int idx = best_idx[row];
    const float2 wv = *(const float2*)(W + (size_t)idx * DIM + l * 2);
    const float2 xv = *(const float2*)(x + (size_t)row * DIM + l * 2);
    const float d0 = wv.x - xv.x, d1 = wv.y - xv.y;
    float part = fmaf(d0, d0, d1 * d1);
    *(float2*)(out0 + (size_t)row * DIM + l * 2) = wv;
    *(float2*)(out1 + (size_t)row * DIM + l * 2) = wv;
    #pragma unroll
    for (int off = 32; off > 0; off >>= 1) part += __shfl_down(part, off, 64);
    if (l == 0) atomicAdd(loss_acc, part);
}

// ---------------- K4: finalize loss ----------------
__global__ void k_loss(const float* __restrict__ loss_acc, float* __restrict__ out_loss) {
    const float S = loss_acc[0];
    // loss = q_latent + 0.25*e_latent; both equal mean((q-x)^2) in forward value
    out_loss[0] = S * 1.25f / (float)(NROWS * DIM);
}

extern "C" void kernel_launch(void* const* d_in, const int* in_sizes, int n_in,
                              void* d_out, int out_size, void* d_ws, size_t ws_size,
                              hipStream_t stream) {
    const float* x = (const float*)d_in[0];   // [32768,128]
    const float* W = (const float*)d_in[1];   // [4096,128]
    float* out = (float*)d_out;

    // d_out flat f32 layout: q2d | q_st | loss | idx
    float* out_q2d  = out;
    float* out_qst  = out + (size_t)NROWS * DIM;
    float* out_loss = out + (size_t)2 * NROWS * DIM;
    float* out_idx  = out + (size_t)2 * NROWS * DIM + 1;

    // ws layout (floats)
    float* ws       = (float*)d_ws;
    float* sww      = ws;                               // 4096
    float* sxx      = ws + 4096;                        // 32768
    int*   best_idx = (int*)(ws + 4096 + 32768);        // 32768
    float* pb_val   = ws + 4096 + 2 * 32768;            // 4*32768
    int*   pb_idx   = (int*)(ws + 4096 + 2 * 32768 + NSPLIT * NROWS);  // 4*32768
    float* loss_acc = ws + 4096 + 2 * 32768 + 2 * NSPLIT * NROWS;      // 1

    hipMemsetAsync(loss_acc, 0, sizeof(float), stream);
    k_pairwise_sq<<<NEMB / 32, 256, 0, stream>>>(W, sww);
    k_pairwise_sq<<<NROWS / 32, 256, 0, stream>>>(x, sxx);
    dim3 g2(NROWS / BM, NSPLIT);
    k_score<<<g2, 256, 0, stream>>>(x, W, sxx, sww, pb_val, pb_idx);
    k_merge<<<NROWS / 256, 256, 0, stream>>>(pb_val, pb_idx, best_idx, out_idx);
    k_quant<<<NROWS / 4, 256, 0, stream>>>(x, W, best_idx, out_q2d, out_qst, loss_acc);
    k_loss<<<1, 1, 0, stream>>>(loss_acc, out_loss);
}

// Round 4
// 264.495 us; speedup vs baseline: 3.4994x; 3.4994x over previous
//
#include <hip/hip_runtime.h>
#include <hip/hip_bf16.h>

#define NEMB  4096
#define DIM   128
#define NROWS 32768
#define CSPL  32          // 4096/128 column blocks

typedef _Float16 half8  __attribute__((ext_vector_type(8)));
typedef _Float16 half4v __attribute__((ext_vector_type(4)));
typedef float    float4v __attribute__((ext_vector_type(4)));

typedef const __attribute__((address_space(1))) void* gas_ptr;
typedef __attribute__((address_space(3))) void*       las_ptr;

__device__ __forceinline__ void gload16(const void* g, void* l) {
    __builtin_amdgcn_global_load_lds((gas_ptr)g, (las_ptr)l, 16, 0, 0);
}

// ---------------- K0: split src*scale into fp16 hi+lo ----------------
// scale is a power of 2 (exact). hi = fp16_rn(v*scale); lo = fp16_rn(v*scale - hi).
__global__ void k_split(const float* __restrict__ src, _Float16* __restrict__ hi,
                        _Float16* __restrict__ lo, float scale) {
    const int i = blockIdx.x * 256 + threadIdx.x;      // float4 index
    const float4 v = ((const float4*)src)[i];
    const float a0 = v.x * scale, a1 = v.y * scale, a2 = v.z * scale, a3 = v.w * scale;
    const _Float16 h0 = (_Float16)a0, h1 = (_Float16)a1, h2 = (_Float16)a2, h3 = (_Float16)a3;
    const _Float16 l0 = (_Float16)(a0 - (float)h0), l1 = (_Float16)(a1 - (float)h1);
    const _Float16 l2 = (_Float16)(a2 - (float)h2), l3 = (_Float16)(a3 - (float)h3);
    half4v hv = {h0, h1, h2, h3}, lv = {l0, l1, l2, l3};
    *(half4v*)(hi + (size_t)i * 4) = hv;
    *(half4v*)(lo + (size_t)i * 4) = lv;
}

// ---------------- K1: numpy-pairwise row sum of squares (exact fp32 semantics) ----------------
__global__ void k_pairwise_sq(const float* __restrict__ src, float* __restrict__ dst) {
    const int wave = (blockIdx.x << 2) | (threadIdx.x >> 6);
    const int l    = threadIdx.x & 63;
    const int row  = wave * 8 + (l >> 3);
    const int j    = l & 7;
    const float* p = src + (size_t)row * DIM + j;
    float v = p[0];
    float r = __fmul_rn(v, v);
    #pragma unroll
    for (int t = 1; t < 16; ++t) { v = p[t * 8]; r = __fadd_rn(r, __fmul_rn(v, v)); }
    float o = __shfl_xor(r, 1, 64); r = __fadd_rn(r, o);
    o = __shfl_xor(r, 2, 64); r = __fadd_rn(r, o);
    o = __shfl_xor(r, 4, 64); r = __fadd_rn(r, o);
    if (j == 0) dst[row] = r;
}

// ---------------- K2: MFMA distances + per-colblock argmin ----------------
// acc = x'*W''^T at scale 2^27 (hh + hl + lh fp16 MFMAs); d = fl(fl(sxx+sww) - acc*2^-26)
__launch_bounds__(256)
__global__ void k_score(const _Float16* __restrict__ Xh, const _Float16* __restrict__ Xl,
                        const _Float16* __restrict__ Wh, const _Float16* __restrict__ Wl,
                        const float* __restrict__ sxx, const float* __restrict__ sww,
                        float* __restrict__ pb_val, int* __restrict__ pb_idx) {
    __shared__ _Float16 sAh[128 * 32], sAl[128 * 32], sBh[128 * 32], sBl[128 * 32];
    __shared__ float ssx[128], ssw[128];

    const int tid  = threadIdx.x;
    const int wv   = tid >> 6;
    const int lane = tid & 63;
    const int l15  = lane & 15;
    const int quad = lane >> 4;
    const int r0   = blockIdx.x * 128;
    const int cb   = blockIdx.y * 128;

    if (tid < 128) ssx[tid] = sxx[r0 + tid];
    else           ssw[tid - 128] = sww[cb + tid - 128];

    float4v acc[2][8];
    #pragma unroll
    for (int tm = 0; tm < 2; ++tm)
        #pragma unroll
        for (int tn = 0; tn < 8; ++tn) acc[tm][tn] = (float4v){0.f, 0.f, 0.f, 0.f};

    const int gr = lane >> 2;            // row within 16-row staging slab
    const int gk = (lane & 3) * 8;       // k offset within 32-k chunk

    for (int c = 0; c < 4; ++c) {
        const int k0 = c * 32;
        __syncthreads();
        #pragma unroll
        for (int rep = 0; rep < 2; ++rep) {
            const int j16 = (wv + rep * 4) * 16;
            const size_t goff = (size_t)(j16 + gr) * DIM + k0 + gk;
            gload16(Xh + (size_t)r0 * DIM + goff, &sAh[j16 * 32]);
            gload16(Xl + (size_t)r0 * DIM + goff, &sAl[j16 * 32]);
            gload16(Wh + (size_t)cb * DIM + goff, &sBh[j16 * 32]);
            gload16(Wl + (size_t)cb * DIM + goff, &sBl[j16 * 32]);
        }
        __syncthreads();

        const int m0 = wv * 32;
        const half8 ah0 = *(const half8*)&sAh[(m0 + l15) * 32 + quad * 8];
        const half8 al0 = *(const half8*)&sAl[(m0 + l15) * 32 + quad * 8];
        const half8 ah1 = *(const half8*)&sAh[(m0 + 16 + l15) * 32 + quad * 8];
        const half8 al1 = *(const half8*)&sAl[(m0 + 16 + l15) * 32 + quad * 8];
        #pragma unroll
        for (int tn = 0; tn < 8; ++tn) {
            const half8 bh = *(const half8*)&sBh[(tn * 16 + l15) * 32 + quad * 8];
            const half8 bl = *(const half8*)&sBl[(tn * 16 + l15) * 32 + quad * 8];
            acc[0][tn] = __builtin_amdgcn_mfma_f32_16x16x32_f16(ah0, bh, acc[0][tn], 0, 0, 0);
            acc[1][tn] = __builtin_amdgcn_mfma_f32_16x16x32_f16(ah1, bh, acc[1][tn], 0, 0, 0);
            acc[0][tn] = __builtin_amdgcn_mfma_f32_16x16x32_f16(ah0, bl, acc[0][tn], 0, 0, 0);
            acc[1][tn] = __builtin_amdgcn_mfma_f32_16x16x32_f16(ah1, bl, acc[1][tn], 0, 0, 0);
            acc[0][tn] = __builtin_amdgcn_mfma_f32_16x16x32_f16(al0, bh, acc[0][tn], 0, 0, 0);
            acc[1][tn] = __builtin_amdgcn_mfma_f32_16x16x32_f16(al1, bh, acc[1][tn], 0, 0, 0);
        }
    }

    // epilogue: C/D layout col=lane&15, row=quad*4+reg. Min with lowest-index ties.
    #pragma unroll
    for (int tm = 0; tm < 2; ++tm) {
        #pragma unroll
        for (int r = 0; r < 4; ++r) {
            const int rl = wv * 32 + tm * 16 + quad * 4 + r;
            const float sx = ssx[rl];
            float bv = 3.0e38f; int bi = 0x7fffffff;
            #pragma unroll
            for (int tn = 0; tn < 8; ++tn) {
                const int cl = tn * 16 + l15;
                const float d = __fsub_rn(__fadd_rn(sx, ssw[cl]),
                                          __fmul_rn(acc[tm][tn][r], 0x1p-26f));
                if (d < bv) { bv = d; bi = cb + cl; }   // tn ascending -> lowest col kept
            }
            #pragma unroll
            for (int off = 1; off < 16; off <<= 1) {
                const float ov = __shfl_xor(bv, off, 64);
                const int   oi = __shfl_xor(bi, off, 64);
                if (ov < bv || (ov == bv && oi < bi)) { bv = ov; bi = oi; }
            }
            if (l15 == 0) {
                pb_val[(size_t)blockIdx.y * NROWS + r0 + rl] = bv;
                pb_idx[(size_t)blockIdx.y * NROWS + r0 + rl] = bi;
            }
        }
    }
}

// ---------------- K2b: merge 32 col-blocks (min, lowest-index ties) ----------------
__global__ void k_merge(const float* __restrict__ pb_val, const int* __restrict__ pb_idx,
                        int* __restrict__ best_idx, float* __restrict__ out_idx) {
    const int r = blockIdx.x * 256 + threadIdx.x;
    float bv = pb_val[r];
    int   bi = pb_idx[r];
    #pragma unroll 4
    for (int s = 1; s < CSPL; ++s) {
        const float v = pb_val[(size_t)s * NROWS + r];
        const int   c = pb_idx[(size_t)s * NROWS + r];
        if (v < bv || (v == bv && c < bi)) { bv = v; bi = c; }
    }
    best_idx[r] = bi;
    out_idx[r] = (float)bi;
}

// ---------------- K3: gather quantized (x2 outputs) + per-row loss partial (NO atomics) ----
__global__ void k_quant(const float* __restrict__ x, const float* __restrict__ W,
                        const int* __restrict__ best_idx,
                        float* __restrict__ out0, float* __restrict__ out1,
                        float* __restrict__ part) {
    const int row = blockIdx.x * 4 + (threadIdx.x >> 6);
    const int l   = threadIdx.x & 63;
    const int idx = best_idx[row];
    const float2 wv = *(const float2*)(W + (size_t)idx * DIM + l * 2);
    const float2 xv = *(const float2*)(x + (size_t)row * DIM + l * 2);
    const float d0 = wv.x - xv.x, d1 = wv.y - xv.y;
    float p = fmaf(d0, d0, d1 * d1);
    *(float2*)(out0 + (size_t)row * DIM + l * 2) = wv;
    *(float2*)(out1 + (size_t)row * DIM + l * 2) = wv;
    #pragma unroll
    for (int off = 32; off > 0; off >>= 1) p += __shfl_down(p, off, 64);
    if (l == 0) part[row] = p;
}

// ---------------- K4: reduce 32768 partials -> loss ----------------
__global__ void k_lsum(const float* __restrict__ part, float* __restrict__ out_loss) {
    __shared__ float red[256];
    const int tid = threadIdx.x;
    float s = 0.f;
    for (int i = tid; i < NROWS; i += 256) s += part[i];
    red[tid] = s;
    __syncthreads();
    #pragma unroll
    for (int w = 128; w > 0; w >>= 1) {
        if (tid < w) red[tid] += red[tid + w];
        __syncthreads();
    }
    if (tid == 0) out_loss[0] = red[0] * 1.25f / (float)(NROWS * DIM);
}

extern "C" void kernel_launch(void* const* d_in, const int* in_sizes, int n_in,
                              void* d_out, int out_size, void* d_ws, size_t ws_size,
                              hipStream_t stream) {
    const float* x = (const float*)d_in[0];   // [32768,128]
    const float* W = (const float*)d_in[1];   // [4096,128]
    float* out = (float*)d_out;

    float* out_q2d  = out;
    float* out_qst  = out + (size_t)NROWS * DIM;
    float* out_loss = out + (size_t)2 * NROWS * DIM;
    float* out_idx  = out + (size_t)2 * NROWS * DIM + 1;

    // ws layout (floats): ~27.7 MB
    float* ws       = (float*)d_ws;
    float* sww      = ws;                                   // 4096
    float* sxx      = ws + 4096;                            // 32768
    int*   best_idx = (int*)(ws + 4096 + 32768);            // 32768
    float* part     = ws + 4096 + 2 * 32768;                // 32768
    float* pb_val   = ws + 4096 + 3 * 32768;                // 32*32768
    int*   pb_idx   = (int*)(pb_val + (size_t)CSPL * NROWS);// 32*32768
    float* fbase    = pb_val + (size_t)2 * CSPL * NROWS;
    _Float16* Xh = (_Float16*)fbase;                        // 32768*128 halfs
    _Float16* Xl = Xh + (size_t)NROWS * DIM;
    _Float16* Wh = Xl + (size_t)NROWS * DIM;                // 4096*128 halfs
    _Float16* Wl = Wh + (size_t)NEMB * DIM;

    // split: x*2^11, W*2^16  (product scale 2^27; both lo terms stay fp16-normal)
    k_split<<<(NROWS * DIM / 4) / 256, 256, 0, stream>>>(x, Xh, Xl, 2048.0f);
    k_split<<<(NEMB * DIM / 4) / 256, 256, 0, stream>>>(W, Wh, Wl, 65536.0f);
    k_pairwise_sq<<<NEMB / 32, 256, 0, stream>>>(W, sww);
    k_pairwise_sq<<<NROWS / 32, 256, 0, stream>>>(x, sxx);
    dim3 g2(NROWS / 128, CSPL);
    k_score<<<g2, 256, 0, stream>>>(Xh, Xl, Wh, Wl, sxx, sww, pb_val, pb_idx);
    k_merge<<<NROWS / 256, 256, 0, stream>>>(pb_val, pb_idx, best_idx, out_idx);
    k_quant<<<NROWS / 4, 256, 0, stream>>>(x, W, best_idx, out_q2d, out_qst, part);
    k_lsum<<<1, 256, 0, stream>>>(part, out_loss);
}